// Round 9
// baseline (117.805 us; speedup 1.0000x reference)
//
#include <hip/hip_runtime.h>
#include <math.h>

#define N_ANCH 13824   // 24*24*24
#define K_TOP 60
#define K_NMS 20
#define AVG_TOPN 7
#define CAP_G 511      // survivor entries per image in ws (+1 count slot = 512*8B = 4KB/image)
// Conservative prune pivot: z = 2.25 -> float bits 0x40100000 -> mono key 0xC0100000.
// ~169 +/- 13 survivors/image for N(0,1) logits; needs >=60 and <=CAP_G, else exact fallback.
#define PIVOT_KEY 0xC0100000u

__device__ __forceinline__ unsigned mono_key(float x) {
  unsigned m = __float_as_uint(x);
  return (m & 0x80000000u) ? ~m : (m | 0x80000000u);
}

// ---- Kernel A: stream Cls, prune, compact survivor list into d_ws ----
__global__ __launch_bounds__(1024)
void prune_kernel(const float* __restrict__ Cls, unsigned long long* __restrict__ W) {
  __shared__ unsigned int cnt2;
  const int b = blockIdx.x;
  const int t = threadIdx.x;
  const int lane = t & 63;
  const size_t cbase = (size_t)b * N_ANCH;

  if (t == 0) cnt2 = 0;
  const float4* C4 = (const float4*)(Cls + cbase);   // 3456 float4 over 1024 threads
  float4 v0 = C4[t];
  float4 v1 = C4[1024 + t];
  float4 v2 = C4[2048 + t];
  const bool tail = (t < 384);
  float4 v3 = tail ? C4[3072 + t] : make_float4(0.f, 0.f, 0.f, 0.f);
  __syncthreads();                           // B1: cnt2 init visible (loads drain here too)

  unsigned k[16];
  k[0]  = mono_key(v0.x); k[1]  = mono_key(v0.y); k[2]  = mono_key(v0.z); k[3]  = mono_key(v0.w);
  k[4]  = mono_key(v1.x); k[5]  = mono_key(v1.y); k[6]  = mono_key(v1.z); k[7]  = mono_key(v1.w);
  k[8]  = mono_key(v2.x); k[9]  = mono_key(v2.y); k[10] = mono_key(v2.z); k[11] = mono_key(v2.w);
  if (tail) {
    k[12] = mono_key(v3.x); k[13] = mono_key(v3.y); k[14] = mono_key(v3.z); k[15] = mono_key(v3.w);
  } else {
    k[12] = 0u; k[13] = 0u; k[14] = 0u; k[15] = 0u;   // never survive
  }

  int cnt = 0;
  #pragma unroll
  for (int q = 0; q < 16; ++q) cnt += (k[q] > PIVOT_KEY) ? 1 : 0;

  // wave-aggregated compaction: exclusive prefix within wave + one LDS atomic per wave
  int pfx = cnt;
  #pragma unroll
  for (int d = 1; d < 64; d <<= 1) {
    int o = __shfl_up(pfx, d, 64);
    if (lane >= d) pfx += o;
  }
  const int excl = pfx - cnt;
  int wtot = __shfl(pfx, 63, 64);
  unsigned wbase = 0;
  if (lane == 63) wbase = atomicAdd(&cnt2, (unsigned)wtot);
  wbase = (unsigned)__shfl((int)wbase, 63, 64);

  unsigned long long* Wb = W + (size_t)b * (CAP_G + 1);
  {
    int off = (int)wbase + excl;
    #pragma unroll
    for (int q = 0; q < 16; ++q) {
      if (k[q] > PIVOT_KEY) {
        int base_i = (q < 4) ? (t << 2) : (q < 8) ? ((1024 + t) << 2)
                     : (q < 12) ? ((2048 + t) << 2) : ((3072 + t) << 2);
        int i = base_i + (q & 3);
        if (off < CAP_G)
          Wb[1 + off] = ((unsigned long long)k[q] << 32) | (unsigned)(~i);
        off++;
      }
    }
  }
  __syncthreads();                           // B2: all cnt2 adds done
  if (t == 0) Wb[0] = (unsigned long long)cnt2;   // may exceed CAP_G -> B falls back
}

// ---- Kernel B: rank, det build, IoU, NMS — small blocks, cheap barriers ----
__global__ __launch_bounds__(256)
void nms_kernel(const float* __restrict__ Cls,
                const float* __restrict__ Shp,
                const float* __restrict__ Off,
                const unsigned long long* __restrict__ W,
                float* __restrict__ Out) {
  __shared__ __align__(16) unsigned long long list[CAP_G + 1];   // 4 KB
  __shared__ float det[K_TOP][9];            // stride 9: bank-conflict-free gathers
  __shared__ unsigned long long Mrow[K_TOP]; // adjacency masks (self-bit preset)

  const int b = blockIdx.x;
  const int t = threadIdx.x;
  const int lane = t & 63;
  const size_t cbase = (size_t)b * N_ANCH;
  const unsigned long long* Wb = W + (size_t)b * (CAP_G + 1);

  if (t < K_TOP) Mrow[t] = 1ull << t;        // diagonal: (ar == idx) term

  const int tot = (int)(unsigned)Wb[0];
  const bool fast = (tot >= K_TOP) && (tot <= CAP_G);
  const int stot = fast ? tot : 0;
  if (t < stot) list[t] = Wb[1 + t];                     // coalesced staging
  if (t + 256 < stot) list[t + 256] = Wb[1 + t + 256];
  __syncthreads();                           // B1: list staged, Mrow init visible

  // Composite keys are unique -> ranks are a permutation; r < 60 builds det[r].
  // Matches lax.top_k order: value desc, ties by ascending index.
  if (fast) {
    for (int s = t; s < tot; s += 256) {     // one entry/thread (two only if tot>256)
      const unsigned long long e = list[s];
      const int i = (int)(~(unsigned)(e & 0xffffffffull));
      // issue the 6 scattered gathers NOW; latency hides under the ranking loop
      size_t bb = (size_t)b * 3 * N_ANCH + (size_t)i;
      float o0 = Off[bb], o1 = Off[bb + N_ANCH], o2 = Off[bb + 2 * N_ANCH];
      float s0 = Shp[bb], s1 = Shp[bb + N_ANCH], s2 = Shp[bb + 2 * N_ANCH];
      int r = 0;
      const ulonglong2* L2 = (const ulonglong2*)list;
      const int half = tot >> 1;
      for (int j2 = 0; j2 < half; ++j2) {    // b128 same-address broadcast reads
        ulonglong2 p = L2[j2];
        r += (p.x > e) ? 1 : 0;
        r += (p.y > e) ? 1 : 0;
      }
      if (tot & 1) r += (list[tot - 1] > e) ? 1 : 0;
      if (r < K_TOP) {
        unsigned m = (unsigned)(e >> 32);
        unsigned bits = (m & 0x80000000u) ? (m & 0x7fffffffu) : ~m;
        float lg = __uint_as_float(bits);
        int iz = i / 576;
        int r2 = i - iz * 576;
        int iy = r2 / 24;
        int ix = r2 - iy * 24;
        det[r][0] = 1.0f;
        det[r][1] = 1.0f / (1.0f + expf(-lg));
        det[r][2] = ((float)iz + o0) * 4.0f; // stride = 96/24 = 4
        det[r][3] = ((float)iy + o1) * 4.0f;
        det[r][4] = ((float)ix + o2) * 4.0f;
        det[r][5] = s0;
        det[r][6] = s1;
        det[r][7] = s2;
      }
    }
  } else {
    // Exact fallback (never taken on bench data; pivot margin > 8 sigma):
    // brute-force rank of every element over global Cls. Slow but exact.
    for (int i = t; i < N_ANCH; i += 256) {
      unsigned ki = mono_key(Cls[cbase + i]);
      unsigned long long e = ((unsigned long long)ki << 32) | (unsigned)(~i);
      int r = 0;
      for (int j = 0; j < N_ANCH; ++j) {
        unsigned kj = mono_key(Cls[cbase + j]);
        unsigned long long ej = ((unsigned long long)kj << 32) | (unsigned)(~j);
        r += (ej > e) ? 1 : 0;
      }
      if (r < K_TOP) {
        unsigned m = (unsigned)(e >> 32);
        unsigned bits = (m & 0x80000000u) ? (m & 0x7fffffffu) : ~m;
        float lg = __uint_as_float(bits);
        int iz = i / 576;
        int r2 = i - iz * 576;
        int iy = r2 / 24;
        int ix = r2 - iy * 24;
        size_t bb = (size_t)b * 3 * N_ANCH + (size_t)i;
        det[r][0] = 1.0f;
        det[r][1] = 1.0f / (1.0f + expf(-lg));
        det[r][2] = ((float)iz + Off[bb]) * 4.0f;
        det[r][3] = ((float)iy + Off[bb + N_ANCH]) * 4.0f;
        det[r][4] = ((float)ix + Off[bb + 2 * N_ANCH]) * 4.0f;
        det[r][5] = Shp[bb];
        det[r][6] = Shp[bb + N_ANCH];
        det[r][7] = Shp[bb + 2 * N_ANCH];
      }
    }
  }
  __syncthreads();                           // B2: det complete

  // ---- adjacency masks, SYMMETRIC (1800 round-robin pairs, both bits) ----
  // Pair set: (ii, (ii+1+k)%60), k in [0,30). d=30 pairs occur twice -> idempotent OR.
  for (int p = t; p < 1800; p += 256) {
    int ii = p / 30;
    int kk = p - ii * 30;
    int jj = ii + 1 + kk; if (jj >= 60) jj -= 60;
    float cz1 = det[ii][2], cy1 = det[ii][3], cx1 = det[ii][4];
    float sz1 = det[ii][5], sy1 = det[ii][6], sx1 = det[ii][7];
    float cz2 = det[jj][2], cy2 = det[jj][3], cx2 = det[jj][4];
    float sz2 = det[jj][5], sy2 = det[jj][6], sx2 = det[jj][7];
    float lz1 = cz1 - 0.5f * sz1, hz1 = cz1 + 0.5f * sz1;
    float ly1 = cy1 - 0.5f * sy1, hy1 = cy1 + 0.5f * sy1;
    float lx1 = cx1 - 0.5f * sx1, hx1 = cx1 + 0.5f * sx1;
    float lz2 = cz2 - 0.5f * sz2, hz2 = cz2 + 0.5f * sz2;
    float ly2 = cy2 - 0.5f * sy2, hy2 = cy2 + 0.5f * sy2;
    float lx2 = cx2 - 0.5f * sx2, hx2 = cx2 + 0.5f * sx2;
    float dz = fmaxf(fminf(hz1, hz2) - fmaxf(lz1, lz2), 0.0f);
    float dy = fmaxf(fminf(hy1, hy2) - fmaxf(ly1, ly2), 0.0f);
    float dx = fmaxf(fminf(hx1, hx2) - fmaxf(lx1, lx2), 0.0f);
    float inter = (dz * dy) * dx;
    float v1 = (sz1 * sy1) * sx1;
    float v2 = (sz2 * sy2) * sx2;
    float iouv = inter / (v1 + v2 - inter);
    if (iouv > 0.05f) {
      atomicOr(&Mrow[ii], 1ull << jj);
      atomicOr(&Mrow[jj], 1ull << ii);
    }
  }
  __syncthreads();                           // B3: Mrow complete

  // ---- NMS: waves 0-2 redundantly run the cheap mask chain; each lane
  //      captures its (step, column) slice and computes the payload in parallel ----
  const int w = t >> 6;
  if (w < 3) {
    const bool in = (lane < K_TOP);
    float myscore = in ? det[lane][1] : 0.0f;
    unsigned long long M = in ? Mrow[lane] : 0ull;
    unsigned long long validm = __ballot(in && (myscore > 0.15f));
    unsigned long long suppressed = 0ull;
    float* outb = Out + (size_t)b * K_NMS * 8;

    const int my_s = (w << 3) + (lane >> 3);   // wave0: steps 0-7, wave1: 8-15, wave2: 16-23
    const int c = lane & 7;
    const bool active = (my_s < K_NMS);
    unsigned long long my_matched = 0ull;
    int my_idx = 0;
    bool my_any = false;

    #pragma unroll
    for (int step = 0; step < K_NMS; ++step) {
      unsigned long long avail = validm & ~suppressed;   // wave-uniform chain
      const bool any = (avail != 0ull);
      int idx = any ? (int)__builtin_ctzll(avail) : 0;
      unsigned mlo = (unsigned)__builtin_amdgcn_readlane((int)(unsigned)(M & 0xffffffffull), idx);
      unsigned mhi = (unsigned)__builtin_amdgcn_readlane((int)(unsigned)(M >> 32), idx);
      unsigned long long matched = any ? (avail & (((unsigned long long)mhi << 32) | mlo)) : 0ull;
      if (step == my_s) { my_matched = matched; my_idx = idx; my_any = any; }
      suppressed |= matched;
    }

    if (active) {
      int cm = __popcll(my_matched);
      int top_n = cm < AVG_TOPN ? cm : AVG_TOPN;
      float sum = 0.0f;
      unsigned long long mm = my_matched;
      #pragma unroll
      for (int q = 0; q < AVG_TOPN; ++q) {     // ascending-index accumulation
        int bq = mm ? (int)__builtin_ctzll(mm) : 0;
        if (q < top_n) sum += det[bq][c];
        mm &= mm - 1ull;
      }
      float r = sum / (float)(top_n > 0 ? top_n : 1);
      if (c == 0) r = 1.0f;
      if (c == 1) r = det[my_idx][1];
      if (!my_any) r = -1.0f;
      outb[my_s * 8 + c] = r;
    }
  }
}

extern "C" void kernel_launch(void* const* d_in, const int* in_sizes, int n_in,
                              void* d_out, int out_size, void* d_ws, size_t ws_size,
                              hipStream_t stream) {
  const float* Cls = (const float*)d_in[0];
  const float* Shp = (const float*)d_in[1];
  const float* Off = (const float*)d_in[2];
  float* Out = (float*)d_out;
  unsigned long long* W = (unsigned long long*)d_ws;   // 256 * 4 KB = 1 MB used
  int B = in_sizes[0] / N_ANCH;   // 256
  prune_kernel<<<B, 1024, 0, stream>>>(Cls, W);
  nms_kernel<<<B, 256, 0, stream>>>(Cls, Shp, Off, W, Out);
}

// Round 10
// 115.199 us; speedup vs baseline: 1.0226x; 1.0226x over previous
//
#include <hip/hip_runtime.h>
#include <math.h>

#define N_ANCH 13824   // 24*24*24
#define TPB 1024
#define K_TOP 60
#define K_NMS 20
#define AVG_TOPN 7
#define CAP 2048       // survivor list capacity (16 KB LDS); overflow -> exact fallback
// Conservative prune pivot: z = 2.25 -> float bits 0x40100000 -> mono key 0xC0100000.
// ~169 +/- 13 survivors/image for N(0,1) logits; needs >=60 and <=CAP, else exact fallback.
#define PIVOT_KEY 0xC0100000u

__device__ __forceinline__ unsigned mono_key(float x) {
  unsigned m = __float_as_uint(x);
  return (m & 0x80000000u) ? ~m : (m | 0x80000000u);
}

__global__ __launch_bounds__(TPB)
void detpp_kernel(const float* __restrict__ Cls,
                  const float* __restrict__ Shp,
                  const float* __restrict__ Off,
                  float* __restrict__ Out) {
  __shared__ __align__(16) unsigned long long list[CAP];   // 16 KB survivor list
  __shared__ float det[K_TOP][9];            // stride 9: bank-conflict-free gathers
  __shared__ unsigned long long Mrow[K_TOP]; // adjacency masks (ballot-built, no init)
  __shared__ unsigned int wcounts[16];       // per-wave survivor counts (no init needed)

  const int b = blockIdx.x;
  const int t = threadIdx.x;
  const int lane = t & 63;
  const int w = t >> 6;
  const size_t cbase = (size_t)b * N_ANCH;

  // ---- Phase 1: load Cls (float4); process keys AS LOADS ARRIVE (no init barrier) ----
  const float4* C4 = (const float4*)(Cls + cbase);   // 3456 float4 over 1024 threads
  float4 v0 = C4[t];
  float4 v1 = C4[1024 + t];
  float4 v2 = C4[2048 + t];
  const bool tail = (t < 384);
  float4 v3 = tail ? C4[3072 + t] : make_float4(0.f, 0.f, 0.f, 0.f);

  unsigned k[16];
  k[0]  = mono_key(v0.x); k[1]  = mono_key(v0.y); k[2]  = mono_key(v0.z); k[3]  = mono_key(v0.w);
  k[4]  = mono_key(v1.x); k[5]  = mono_key(v1.y); k[6]  = mono_key(v1.z); k[7]  = mono_key(v1.w);
  k[8]  = mono_key(v2.x); k[9]  = mono_key(v2.y); k[10] = mono_key(v2.z); k[11] = mono_key(v2.w);
  if (tail) {
    k[12] = mono_key(v3.x); k[13] = mono_key(v3.y); k[14] = mono_key(v3.z); k[15] = mono_key(v3.w);
  } else {
    k[12] = 0u; k[13] = 0u; k[14] = 0u; k[15] = 0u;   // never survive
  }

  int cnt = 0;
  #pragma unroll
  for (int q = 0; q < 16; ++q) cnt += (k[q] > PIVOT_KEY) ? 1 : 0;

  // wave-level exclusive prefix; per-wave total into its own wcounts slot (no atomic)
  int pfx = cnt;
  #pragma unroll
  for (int d = 1; d < 64; d <<= 1) {
    int o = __shfl_up(pfx, d, 64);
    if (lane >= d) pfx += o;
  }
  const int excl = pfx - cnt;
  if (lane == 63) wcounts[w] = (unsigned)pfx;   // wave total
  __syncthreads();                           // B1: wcounts complete

  unsigned wbase = 0, total = 0;
  #pragma unroll
  for (int w2 = 0; w2 < 16; ++w2) {          // broadcast LDS reads
    unsigned c = wcounts[w2];
    if (w2 < w) wbase += c;
    total += c;
  }

  {
    int off = (int)wbase + excl;
    #pragma unroll
    for (int q = 0; q < 16; ++q) {
      if (k[q] > PIVOT_KEY) {
        int base_i = (q < 4) ? (t << 2) : (q < 8) ? ((1024 + t) << 2)
                     : (q < 12) ? ((2048 + t) << 2) : ((3072 + t) << 2);
        int i = base_i + (q & 3);
        if (off < CAP)
          list[off] = ((unsigned long long)k[q] << 32) | (unsigned)(~i);
        off++;
      }
    }
  }
  __syncthreads();                           // B2: list complete

  const bool fast = (total >= (unsigned)K_TOP) && (total <= (unsigned)CAP);

  // ---- Phase 2: prefetch gathers, direct ranking, det build from registers ----
  // Composite keys are unique -> ranks are a permutation; r < 60 builds det[r].
  // Matches lax.top_k order: value desc, ties by ascending index.
  if (fast) {
    const int tot = (int)total;
    for (int s = t; s < tot; s += TPB) {     // full coverage for any tot <= CAP
      const unsigned long long e = list[s];
      const int i = (int)(~(unsigned)(e & 0xffffffffull));
      // issue the 6 scattered gathers NOW; latency hides under the ranking loop
      size_t bb = (size_t)b * 3 * N_ANCH + (size_t)i;
      float o0 = Off[bb], o1 = Off[bb + N_ANCH], o2 = Off[bb + 2 * N_ANCH];
      float s0 = Shp[bb], s1 = Shp[bb + N_ANCH], s2 = Shp[bb + 2 * N_ANCH];
      int r = 0;
      const ulonglong2* L2 = (const ulonglong2*)list;
      const int half = tot >> 1;
      for (int j2 = 0; j2 < half; ++j2) {    // b128 same-address broadcast reads
        ulonglong2 p = L2[j2];
        r += (p.x > e) ? 1 : 0;
        r += (p.y > e) ? 1 : 0;
      }
      if (tot & 1) r += (list[tot - 1] > e) ? 1 : 0;
      if (r < K_TOP) {
        unsigned m = (unsigned)(e >> 32);
        unsigned bits = (m & 0x80000000u) ? (m & 0x7fffffffu) : ~m;
        float lg = __uint_as_float(bits);
        int iz = i / 576;
        int r2 = i - iz * 576;
        int iy = r2 / 24;
        int ix = r2 - iy * 24;
        det[r][0] = 1.0f;
        det[r][1] = 1.0f / (1.0f + expf(-lg));
        det[r][2] = ((float)iz + o0) * 4.0f; // stride = 96/24 = 4
        det[r][3] = ((float)iy + o1) * 4.0f;
        det[r][4] = ((float)ix + o2) * 4.0f;
        det[r][5] = s0;
        det[r][6] = s1;
        det[r][7] = s2;
      }
    }
  } else {
    // Exact fallback (never taken on bench data; pivot margin > 8 sigma):
    // brute-force rank of every element over global Cls. Slow but exact.
    for (int i = t; i < N_ANCH; i += TPB) {
      unsigned ki = mono_key(Cls[cbase + i]);
      unsigned long long e = ((unsigned long long)ki << 32) | (unsigned)(~i);
      int r = 0;
      for (int j = 0; j < N_ANCH; ++j) {
        unsigned kj = mono_key(Cls[cbase + j]);
        unsigned long long ej = ((unsigned long long)kj << 32) | (unsigned)(~j);
        r += (ej > e) ? 1 : 0;
      }
      if (r < K_TOP) {
        unsigned m = (unsigned)(e >> 32);
        unsigned bits = (m & 0x80000000u) ? (m & 0x7fffffffu) : ~m;
        float lg = __uint_as_float(bits);
        int iz = i / 576;
        int r2 = i - iz * 576;
        int iy = r2 / 24;
        int ix = r2 - iy * 24;
        size_t bb = (size_t)b * 3 * N_ANCH + (size_t)i;
        det[r][0] = 1.0f;
        det[r][1] = 1.0f / (1.0f + expf(-lg));
        det[r][2] = ((float)iz + Off[bb]) * 4.0f;
        det[r][3] = ((float)iy + Off[bb + N_ANCH]) * 4.0f;
        det[r][4] = ((float)ix + Off[bb + 2 * N_ANCH]) * 4.0f;
        det[r][5] = Shp[bb];
        det[r][6] = Shp[bb + N_ANCH];
        det[r][7] = Shp[bb + 2 * N_ANCH];
      }
    }
  }
  __syncthreads();                           // B3: det complete

  // ---- Phase 3: adjacency via BALLOT — zero atomics, no Mrow init needed ----
  // Wave w computes rows 4w..4w+3; lane j evaluates iou(row, j); self-bit via (j==row).
  // Same fp32 divide-then-compare expression as before (bit-identical decisions).
  #pragma unroll
  for (int it = 0; it < 4; ++it) {
    const int ii = (w << 2) + it;
    bool m = false;
    if (ii < K_TOP && lane < K_TOP) {
      float cz1 = det[ii][2], cy1 = det[ii][3], cx1 = det[ii][4];     // broadcast
      float sz1 = det[ii][5], sy1 = det[ii][6], sx1 = det[ii][7];
      float cz2 = det[lane][2], cy2 = det[lane][3], cx2 = det[lane][4]; // 2-way max
      float sz2 = det[lane][5], sy2 = det[lane][6], sx2 = det[lane][7];
    float lz1 = cz1 - 0.5f * sz1, hz1 = cz1 + 0.5f * sz1;
    float ly1 = cy1 - 0.5f * sy1, hy1 = cy1 + 0.5f * sy1;
    float lx1 = cx1 - 0.5f * sx1, hx1 = cx1 + 0.5f * sx1;
    float lz2 = cz2 - 0.5f * sz2, hz2 = cz2 + 0.5f * sz2;
    float ly2 = cy2 - 0.5f * sy2, hy2 = cy2 + 0.5f * sy2;
    float lx2 = cx2 - 0.5f * sx2, hx2 = cx2 + 0.5f * sx2;
    float dz = fmaxf(fminf(hz1, hz2) - fmaxf(lz1, lz2), 0.0f);
    float dy = fmaxf(fminf(hy1, hy2) - fmaxf(ly1, ly2), 0.0f);
    float dx = fmaxf(fminf(hx1, hx2) - fmaxf(lx1, lx2), 0.0f);
    float inter = (dz * dy) * dx;
    float v1 = (sz1 * sy1) * sx1;
    float v2 = (sz2 * sy2) * sx2;
    float iouv = inter / (v1 + v2 - inter);
      m = (iouv > 0.05f) || (lane == ii);
    }
    unsigned long long bal = __ballot(m);
    if (ii < K_TOP && lane == 0) Mrow[ii] = bal;
  }
  __syncthreads();                           // B4: Mrow complete

  // ---- Phase 4: NMS — waves 0-2 redundantly run the cheap mask chain; each lane
  //      captures its (step, column) slice and computes the payload in parallel ----
  if (w < 3) {
    const bool in = (lane < K_TOP);
    float myscore = in ? det[lane][1] : 0.0f;
    unsigned long long M = in ? Mrow[lane] : 0ull;
    unsigned long long validm = __ballot(in && (myscore > 0.15f));
    unsigned long long suppressed = 0ull;
    float* outb = Out + (size_t)b * K_NMS * 8;

    const int my_s = (w << 3) + (lane >> 3);   // wave0: steps 0-7, wave1: 8-15, wave2: 16-23
    const int c = lane & 7;
    const bool active = (my_s < K_NMS);
    unsigned long long my_matched = 0ull;
    int my_idx = 0;
    bool my_any = false;

    #pragma unroll
    for (int step = 0; step < K_NMS; ++step) {
      unsigned long long avail = validm & ~suppressed;   // wave-uniform chain
      const bool any = (avail != 0ull);
      int idx = any ? (int)__builtin_ctzll(avail) : 0;
      unsigned mlo = (unsigned)__builtin_amdgcn_readlane((int)(unsigned)(M & 0xffffffffull), idx);
      unsigned mhi = (unsigned)__builtin_amdgcn_readlane((int)(unsigned)(M >> 32), idx);
      unsigned long long matched = any ? (avail & (((unsigned long long)mhi << 32) | mlo)) : 0ull;
      if (step == my_s) { my_matched = matched; my_idx = idx; my_any = any; }
      suppressed |= matched;
    }

    if (active) {
      int cm = __popcll(my_matched);
      int top_n = cm < AVG_TOPN ? cm : AVG_TOPN;
      float sum = 0.0f;
      unsigned long long mm = my_matched;
      #pragma unroll
      for (int q = 0; q < AVG_TOPN; ++q) {     // ascending-index accumulation
        int bq = mm ? (int)__builtin_ctzll(mm) : 0;
        if (q < top_n) sum += det[bq][c];
        mm &= mm - 1ull;
      }
      float r = sum / (float)(top_n > 0 ? top_n : 1);
      if (c == 0) r = 1.0f;
      if (c == 1) r = det[my_idx][1];
      if (!my_any) r = -1.0f;
      outb[my_s * 8 + c] = r;
    }
  }
}

extern "C" void kernel_launch(void* const* d_in, const int* in_sizes, int n_in,
                              void* d_out, int out_size, void* d_ws, size_t ws_size,
                              hipStream_t stream) {
  const float* Cls = (const float*)d_in[0];
  const float* Shp = (const float*)d_in[1];
  const float* Off = (const float*)d_in[2];
  float* Out = (float*)d_out;
  int B = in_sizes[0] / N_ANCH;   // 256
  detpp_kernel<<<B, TPB, 0, stream>>>(Cls, Shp, Off, Out);
}

// Round 11
// 112.208 us; speedup vs baseline: 1.0499x; 1.0267x over previous
//
#include <hip/hip_runtime.h>
#include <math.h>

#define N_ANCH 13824   // 24*24*24
#define TPB 1024
#define K_TOP 60
#define K_NMS 20
#define AVG_TOPN 7
#define CAP 2048       // survivor list capacity (16 KB LDS); overflow -> exact fallback
// Conservative prune pivot: z = 2.25 -> float bits 0x40100000 -> mono key 0xC0100000.
// ~169 +/- 13 survivors/image for N(0,1) logits; needs >=60 and <=CAP, else exact fallback.
#define PIVOT_KEY 0xC0100000u

__device__ __forceinline__ unsigned mono_key(float x) {
  unsigned m = __float_as_uint(x);
  return (m & 0x80000000u) ? ~m : (m | 0x80000000u);
}

__global__ __launch_bounds__(TPB)
void detpp_kernel(const float* __restrict__ Cls,
                  const float* __restrict__ Shp,
                  const float* __restrict__ Off,
                  float* __restrict__ Out) {
  __shared__ __align__(16) unsigned long long list[CAP];   // 16 KB survivor list
  __shared__ float det[K_TOP][9];            // stride 9: bank-conflict-free gathers
  __shared__ unsigned long long Mrow[K_TOP]; // adjacency masks (self-bit preset)
  __shared__ unsigned int cnt2;

  const int b = blockIdx.x;
  const int t = threadIdx.x;
  const int lane = t & 63;
  const size_t cbase = (size_t)b * N_ANCH;

  if (t == 0) cnt2 = 0;
  if (t < K_TOP) Mrow[t] = 1ull << t;        // diagonal: (ar == idx) term

  // ---- Phase 1: load Cls (float4); issue before barrier so B1 covers init+loads ----
  const float4* C4 = (const float4*)(Cls + cbase);   // 3456 float4 over 1024 threads
  float4 v0 = C4[t];
  float4 v1 = C4[1024 + t];
  float4 v2 = C4[2048 + t];
  const bool tail = (t < 384);
  float4 v3 = tail ? C4[3072 + t] : make_float4(0.f, 0.f, 0.f, 0.f);
  __syncthreads();                           // B1: cnt2/Mrow init visible

  unsigned k[16];
  k[0]  = mono_key(v0.x); k[1]  = mono_key(v0.y); k[2]  = mono_key(v0.z); k[3]  = mono_key(v0.w);
  k[4]  = mono_key(v1.x); k[5]  = mono_key(v1.y); k[6]  = mono_key(v1.z); k[7]  = mono_key(v1.w);
  k[8]  = mono_key(v2.x); k[9]  = mono_key(v2.y); k[10] = mono_key(v2.z); k[11] = mono_key(v2.w);
  if (tail) {
    k[12] = mono_key(v3.x); k[13] = mono_key(v3.y); k[14] = mono_key(v3.z); k[15] = mono_key(v3.w);
  } else {
    k[12] = 0u; k[13] = 0u; k[14] = 0u; k[15] = 0u;   // never survive
  }

  int cnt = 0;
  #pragma unroll
  for (int q = 0; q < 16; ++q) cnt += (k[q] > PIVOT_KEY) ? 1 : 0;

  // wave-aggregated compaction: exclusive prefix within wave + one atomic per wave
  int pfx = cnt;
  #pragma unroll
  for (int d = 1; d < 64; d <<= 1) {
    int o = __shfl_up(pfx, d, 64);
    if (lane >= d) pfx += o;
  }
  const int excl = pfx - cnt;
  int wtot = __shfl(pfx, 63, 64);
  unsigned wbase = 0;
  if (lane == 63) wbase = atomicAdd(&cnt2, (unsigned)wtot);
  wbase = (unsigned)__shfl((int)wbase, 63, 64);

  {
    int off = (int)wbase + excl;
    #pragma unroll
    for (int q = 0; q < 16; ++q) {
      if (k[q] > PIVOT_KEY) {
        int base_i = (q < 4) ? (t << 2) : (q < 8) ? ((1024 + t) << 2)
                     : (q < 12) ? ((2048 + t) << 2) : ((3072 + t) << 2);
        int i = base_i + (q & 3);
        if (off < CAP)
          list[off] = ((unsigned long long)k[q] << 32) | (unsigned)(~i);
        off++;
      }
    }
  }
  __syncthreads();                           // B2: list complete

  const unsigned total = cnt2;
  const bool fast = (total >= (unsigned)K_TOP) && (total <= (unsigned)CAP);

  // ---- Phase 2: prefetch gathers, direct ranking, det build from registers ----
  // Composite keys are unique -> ranks are a permutation; r < 60 builds det[r].
  // Matches lax.top_k order: value desc, ties by ascending index.
  if (fast) {
    const int tot = (int)total;
    for (int s = t; s < tot; s += TPB) {     // full coverage for any tot <= CAP
      const unsigned long long e = list[s];
      const int i = (int)(~(unsigned)(e & 0xffffffffull));
      // issue the 6 scattered gathers NOW; latency hides under the ranking loop
      size_t bb = (size_t)b * 3 * N_ANCH + (size_t)i;
      float o0 = Off[bb], o1 = Off[bb + N_ANCH], o2 = Off[bb + 2 * N_ANCH];
      float s0 = Shp[bb], s1 = Shp[bb + N_ANCH], s2 = Shp[bb + 2 * N_ANCH];
      int r = 0;
      const ulonglong2* L2 = (const ulonglong2*)list;
      const int half = tot >> 1;
      for (int j2 = 0; j2 < half; ++j2) {    // b128 same-address broadcast reads
        ulonglong2 p = L2[j2];
        r += (p.x > e) ? 1 : 0;
        r += (p.y > e) ? 1 : 0;
      }
      if (tot & 1) r += (list[tot - 1] > e) ? 1 : 0;
      if (r < K_TOP) {
        unsigned m = (unsigned)(e >> 32);
        unsigned bits = (m & 0x80000000u) ? (m & 0x7fffffffu) : ~m;
        float lg = __uint_as_float(bits);
        int iz = i / 576;
        int r2 = i - iz * 576;
        int iy = r2 / 24;
        int ix = r2 - iy * 24;
        det[r][0] = 1.0f;
        det[r][1] = 1.0f / (1.0f + expf(-lg));
        det[r][2] = ((float)iz + o0) * 4.0f; // stride = 96/24 = 4
        det[r][3] = ((float)iy + o1) * 4.0f;
        det[r][4] = ((float)ix + o2) * 4.0f;
        det[r][5] = s0;
        det[r][6] = s1;
        det[r][7] = s2;
      }
    }
  } else {
    // Exact fallback (never taken on bench data; pivot margin > 8 sigma):
    // brute-force rank of every element over global Cls. Slow but exact.
    for (int i = t; i < N_ANCH; i += TPB) {
      unsigned ki = mono_key(Cls[cbase + i]);
      unsigned long long e = ((unsigned long long)ki << 32) | (unsigned)(~i);
      int r = 0;
      for (int j = 0; j < N_ANCH; ++j) {
        unsigned kj = mono_key(Cls[cbase + j]);
        unsigned long long ej = ((unsigned long long)kj << 32) | (unsigned)(~j);
        r += (ej > e) ? 1 : 0;
      }
      if (r < K_TOP) {
        unsigned m = (unsigned)(e >> 32);
        unsigned bits = (m & 0x80000000u) ? (m & 0x7fffffffu) : ~m;
        float lg = __uint_as_float(bits);
        int iz = i / 576;
        int r2 = i - iz * 576;
        int iy = r2 / 24;
        int ix = r2 - iy * 24;
        size_t bb = (size_t)b * 3 * N_ANCH + (size_t)i;
        det[r][0] = 1.0f;
        det[r][1] = 1.0f / (1.0f + expf(-lg));
        det[r][2] = ((float)iz + Off[bb]) * 4.0f;
        det[r][3] = ((float)iy + Off[bb + N_ANCH]) * 4.0f;
        det[r][4] = ((float)ix + Off[bb + 2 * N_ANCH]) * 4.0f;
        det[r][5] = Shp[bb];
        det[r][6] = Shp[bb + N_ANCH];
        det[r][7] = Shp[bb + 2 * N_ANCH];
      }
    }
  }
  __syncthreads();                           // B3: det complete

  // ---- Phase 3: adjacency masks, SYMMETRIC (1800 round-robin pairs, both bits) ----
  // Pair set: (ii, (ii+1+k)%60), k in [0,30). d=30 pairs occur twice -> idempotent OR.
  for (int p = t; p < 1800; p += TPB) {
    int ii = p / 30;
    int kk = p - ii * 30;
    int jj = ii + 1 + kk; if (jj >= 60) jj -= 60;
    float cz1 = det[ii][2], cy1 = det[ii][3], cx1 = det[ii][4];
    float sz1 = det[ii][5], sy1 = det[ii][6], sx1 = det[ii][7];
    float cz2 = det[jj][2], cy2 = det[jj][3], cx2 = det[jj][4];
    float sz2 = det[jj][5], sy2 = det[jj][6], sx2 = det[jj][7];
    float lz1 = cz1 - 0.5f * sz1, hz1 = cz1 + 0.5f * sz1;
    float ly1 = cy1 - 0.5f * sy1, hy1 = cy1 + 0.5f * sy1;
    float lx1 = cx1 - 0.5f * sx1, hx1 = cx1 + 0.5f * sx1;
    float lz2 = cz2 - 0.5f * sz2, hz2 = cz2 + 0.5f * sz2;
    float ly2 = cy2 - 0.5f * sy2, hy2 = cy2 + 0.5f * sy2;
    float lx2 = cx2 - 0.5f * sx2, hx2 = cx2 + 0.5f * sx2;
    float dz = fmaxf(fminf(hz1, hz2) - fmaxf(lz1, lz2), 0.0f);
    float dy = fmaxf(fminf(hy1, hy2) - fmaxf(ly1, ly2), 0.0f);
    float dx = fmaxf(fminf(hx1, hx2) - fmaxf(lx1, lx2), 0.0f);
    float inter = (dz * dy) * dx;
    float v1 = (sz1 * sy1) * sx1;
    float v2 = (sz2 * sy2) * sx2;
    float iouv = inter / (v1 + v2 - inter);
    if (iouv > 0.05f) {
      atomicOr(&Mrow[ii], 1ull << jj);
      atomicOr(&Mrow[jj], 1ull << ii);
    }
  }
  __syncthreads();                           // B4: Mrow complete

  // ---- Phase 4: NMS — waves 0-2 redundantly run the cheap mask chain; each lane
  //      captures its (step, column) slice and computes the payload in parallel ----
  const int w = t >> 6;
  if (w < 3) {
    const bool in = (lane < K_TOP);
    float myscore = in ? det[lane][1] : 0.0f;
    unsigned long long M = in ? Mrow[lane] : 0ull;
    unsigned long long validm = __ballot(in && (myscore > 0.15f));
    unsigned long long suppressed = 0ull;
    float* outb = Out + (size_t)b * K_NMS * 8;

    const int my_s = (w << 3) + (lane >> 3);   // wave0: steps 0-7, wave1: 8-15, wave2: 16-23
    const int c = lane & 7;
    const bool active = (my_s < K_NMS);
    unsigned long long my_matched = 0ull;
    int my_idx = 0;
    bool my_any = false;

    #pragma unroll
    for (int step = 0; step < K_NMS; ++step) {
      unsigned long long avail = validm & ~suppressed;   // wave-uniform chain
      const bool any = (avail != 0ull);
      int idx = any ? (int)__builtin_ctzll(avail) : 0;
      unsigned mlo = (unsigned)__builtin_amdgcn_readlane((int)(unsigned)(M & 0xffffffffull), idx);
      unsigned mhi = (unsigned)__builtin_amdgcn_readlane((int)(unsigned)(M >> 32), idx);
      unsigned long long matched = any ? (avail & (((unsigned long long)mhi << 32) | mlo)) : 0ull;
      if (step == my_s) { my_matched = matched; my_idx = idx; my_any = any; }
      suppressed |= matched;
    }

    if (active) {
      int cm = __popcll(my_matched);
      int top_n = cm < AVG_TOPN ? cm : AVG_TOPN;
      float sum = 0.0f;
      unsigned long long mm = my_matched;
      #pragma unroll
      for (int q = 0; q < AVG_TOPN; ++q) {     // ascending-index accumulation
        int bq = mm ? (int)__builtin_ctzll(mm) : 0;
        if (q < top_n) sum += det[bq][c];
        mm &= mm - 1ull;
      }
      float r = sum / (float)(top_n > 0 ? top_n : 1);
      if (c == 0) r = 1.0f;
      if (c == 1) r = det[my_idx][1];
      if (!my_any) r = -1.0f;
      outb[my_s * 8 + c] = r;
    }
  }
}

extern "C" void kernel_launch(void* const* d_in, const int* in_sizes, int n_in,
                              void* d_out, int out_size, void* d_ws, size_t ws_size,
                              hipStream_t stream) {
  const float* Cls = (const float*)d_in[0];
  const float* Shp = (const float*)d_in[1];
  const float* Off = (const float*)d_in[2];
  float* Out = (float*)d_out;
  int B = in_sizes[0] / N_ANCH;   // 256
  detpp_kernel<<<B, TPB, 0, stream>>>(Cls, Shp, Off, Out);
}